// Round 9
// baseline (679.298 us; speedup 1.0000x reference)
//
#include <hip/hip_runtime.h>

typedef __attribute__((ext_vector_type(8))) short s16x8;
typedef __attribute__((ext_vector_type(4))) float f32x4;
typedef __attribute__((ext_vector_type(4))) unsigned short u16x4;
typedef __attribute__((ext_vector_type(8))) unsigned short u16x8;

#define PAD 136   // GEMM-tile LDS row stride (2-way on 16-row reads = free)
#define LPAD 144  // k_lstm h row stride: row bank offset 8 -> dup-4 read conflict-free; slot 1152B 16B-aligned

__device__ __forceinline__ unsigned short f2bf(float f){
  union{float f;unsigned u;} v; v.f=f;
  unsigned r=v.u + 0x7fffu + ((v.u>>16)&1u);
  return (unsigned short)(r>>16);
}
__device__ __forceinline__ float bf2f(unsigned short u){
  union{unsigned u;float f;} v; v.u=((unsigned)u)<<16; return v.f;
}
__device__ __forceinline__ float ubits2f(unsigned u){
  union{unsigned u;float f;} v; v.u=u; return v.f;
}
__device__ __forceinline__ float rcp_(float x){ return __builtin_amdgcn_rcpf(x); }
__device__ __forceinline__ float e2_(float x){ return __builtin_amdgcn_exp2f(x); }
__device__ __forceinline__ float tanh_(float x){ return 1.f-2.f*rcp_(1.f+e2_(x*2.885390082f)); }

// 128x128x128 bf16 GEMM from LDS tiles. As: [128][PAD] rows=M, Bs: [128][PAD] rows=N (i.e. B^T).
// 8 waves = 2(M) x 4(N). acc[mt][nt]: C[row = wm*64+mt*16+(l>>4)*4+r][col = wn*32+nt*16+(l&15)]
__device__ __forceinline__ void mfma128(const unsigned short* As, const unsigned short* Bs, f32x4 acc[4][2]){
  const int tid=threadIdx.x, w=tid>>6, l=tid&63;
  const int wm=w>>2, wn=w&3, lr=l&15, lk=(l>>4)*8;
#pragma unroll
  for(int kc=0;kc<4;++kc){
    const int ko=kc*32+lk;
    s16x8 a[4], bb[2];
#pragma unroll
    for(int mt=0;mt<4;++mt) a[mt]=*(const s16x8*)(As+(wm*64+mt*16+lr)*PAD+ko);
#pragma unroll
    for(int nt=0;nt<2;++nt) bb[nt]=*(const s16x8*)(Bs+(wn*32+nt*16+lr)*PAD+ko);
#pragma unroll
    for(int mt=0;mt<4;++mt)
#pragma unroll
      for(int nt=0;nt<2;++nt)
        acc[mt][nt]=__builtin_amdgcn_mfma_f32_16x16x32_bf16(a[mt],bb[nt],acc[mt][nt],0,0,0);
  }
}

// ---- W_hh f32 -> bf16, pre-scaled by -log2e (gate g: -2*log2e) ----
__global__ __launch_bounds__(256) void k_cvt(const float* __restrict__ w, unsigned short* __restrict__ o, int n){
  int i = blockIdx.x*256 + threadIdx.x;
  if (i<n){
    int g=(i>>14)&3;
    float s=(g==2)?-2.885390082f:-1.442695041f;
    o[i] = f2bf(w[i]*s);
  }
}

// ---- aspect LN + G_b = circulant(a_b) @ W_att^T, stored GT[b][n][k] bf16 ----
__global__ __launch_bounds__(512) void k_aspg(const int* __restrict__ aspect, const float* __restrict__ emb,
    const float* __restrict__ ang, const float* __restrict__ anb, const float* __restrict__ watt,
    unsigned short* __restrict__ gt){
  __shared__ unsigned short As[128*PAD];
  __shared__ unsigned short Bs[128*PAD];
  __shared__ float a_ln[128];
  __shared__ float stat[2];
  const int b=blockIdx.x, tid=threadIdx.x;
  if (tid<128) a_ln[tid] = emb[(size_t)aspect[b]*128 + tid];
  __syncthreads();
  if (tid==0){
    float s=0.f,q=0.f;
    for(int d=0;d<128;++d){ float v=a_ln[d]; s+=v; q+=v*v; }
    float m=s*(1.f/128.f);
    stat[0]=m; stat[1]=__builtin_amdgcn_rsqf(q*(1.f/128.f)-m*m+1e-5f);
  }
  __syncthreads();
  if (tid<128) a_ln[tid] = (a_ln[tid]-stat[0])*stat[1]*ang[tid]+anb[tid];
  __syncthreads();
  { // A = circulant: As[k][d] = a_ln[(d-k) & 127]
    int k=tid>>2, dq=(tid&3)*32;
    for(int d=dq; d<dq+32; ++d) As[k*PAD+d]=f2bf(a_ln[(d-k)&127]);
  }
  { // B^T rows = n: Bs[n][d] = W_att[n][d]
    int i=tid>>2, kq=(tid&3)*32;
    const f32x4* src=(const f32x4*)(watt+(size_t)i*128+kq);
#pragma unroll
    for(int j=0;j<8;++j){ f32x4 v=src[j]; u16x4 o;
#pragma unroll
      for(int q=0;q<4;++q) o[q]=f2bf(v[q]);
      *(u16x4*)(Bs+i*PAD+kq+4*j)=o; }
  }
  __syncthreads();
  f32x4 z={0.f,0.f,0.f,0.f};
  f32x4 acc[4][2]={{z,z},{z,z},{z,z},{z,z}};
  mfma128(As,Bs,acc);
  const int w=tid>>6,l=tid&63,wm=w>>2,wn=w&3,lr=l&15,lg=l>>4;
#pragma unroll
  for(int mt=0;mt<4;++mt)
#pragma unroll
    for(int nt=0;nt<2;++nt){
      int k0=wm*64+mt*16+lg*4;
      int n=wn*32+nt*16+lr;
      u16x4 o;
#pragma unroll
      for(int r=0;r<4;++r) o[r]=f2bf(acc[mt][nt][r]);
      *(u16x4*)(gt+(size_t)b*16384+n*128+k0)=o;
    }
}

// ---- xW = (emb[tok] @ W_ih^T + b_ih + b_hh) * gate_scale, bf16 xw[t][blk16][n][row4] ----
__global__ __launch_bounds__(512) void k_xw(const int* __restrict__ new_list, const float* __restrict__ emb,
    const float* __restrict__ wih, const float* __restrict__ bih, const float* __restrict__ bhh,
    unsigned short* __restrict__ xw){
  __shared__ unsigned short As[128*PAD];
  __shared__ unsigned short Bs[128*PAD];
  const int tid=threadIdx.x;
  const int m0=blockIdx.x*128, n0=blockIdx.y*128;
  { // A: gathered emb rows (token for (t,b), m = t*64+b)
    int i=tid>>2, kq=(tid&3)*32;
    int m=m0+i, t=m>>6, b=m&63;
    int tok=new_list[b*1024+t];
    const f32x4* src=(const f32x4*)(emb+(size_t)tok*128+kq);
#pragma unroll
    for(int j=0;j<8;++j){ f32x4 v=src[j]; u16x4 o;
#pragma unroll
      for(int q=0;q<4;++q) o[q]=f2bf(v[q]);
      *(u16x4*)(As+i*PAD+kq+4*j)=o; }
  }
  { // B^T rows = n: W_ih[n][k]
    int i=tid>>2, kq=(tid&3)*32;
    const f32x4* src=(const f32x4*)(wih+(size_t)(n0+i)*128+kq);
#pragma unroll
    for(int j=0;j<8;++j){ f32x4 v=src[j]; u16x4 o;
#pragma unroll
      for(int q=0;q<4;++q) o[q]=f2bf(v[q]);
      *(u16x4*)(Bs+i*PAD+kq+4*j)=o; }
  }
  __syncthreads();
  f32x4 z={0.f,0.f,0.f,0.f};
  f32x4 acc[4][2]={{z,z},{z,z},{z,z},{z,z}};
  mfma128(As,Bs,acc);
  const int w=tid>>6,l=tid&63,wm=w>>2,wn=w&3,lr=l&15,lg=l>>4;
#pragma unroll
  for(int nt=0;nt<2;++nt){
    int n=n0+wn*32+nt*16+lr;
    float bias=bih[n]+bhh[n];
    float s=((n>>7)==2)?-2.885390082f:-1.442695041f;
#pragma unroll
    for(int mt=0;mt<4;++mt){
      int m_=m0+wm*64+mt*16+lg*4;
      int t=m_>>6, b0=m_&63;           // b0 is 4-aligned, rows b0..b0+3 same t
      u16x4 o;
#pragma unroll
      for(int r=0;r<4;++r) o[r]=f2bf((acc[mt][nt][r]+bias)*s);
      // layout: [t][b0>>2][n][b0&3]
      *(u16x4*)(xw+(((size_t)t*16+(b0>>2))*512+n)*4)=o;
    }
  }
}

// ---- recurrent LSTM: 16 blocks x 4 batch, dup-x4 A rows; xW as MFMA C-initializer ----
__global__ __launch_bounds__(512) void k_lstm(const unsigned short* __restrict__ xw,
    const unsigned short* __restrict__ whh,
    unsigned short* __restrict__ hraw, float* __restrict__ hL){
  __shared__ unsigned short hbuf[2][4*LPAD];   // slot = 1152B = 72*16 -> 16B aligned
  const int tid=threadIdx.x, w=tid>>6, l=tid&63, lr=l&15, lg=l>>4;
  const int blk=blockIdx.x, bb=blk*4;
  const int cb=w*16+lr;                       // h column this lane owns
  // W_hh B-fragments in registers (step-invariant, pre-scaled). wave w owns cols w*16..+15 / gate.
  s16x8 wf[4][4];
#pragma unroll
  for(int g=0;g<4;++g)
#pragma unroll
    for(int kc=0;kc<4;++kc)
      wf[g][kc]=*(const s16x8*)(whh+(size_t)(g*128+cb)*128+kc*32+lg*8);
  for(int i=tid;i<2*4*LPAD;i+=512) ((unsigned short*)hbuf)[i]=0;
  __syncthreads();
  // xw addressing: [t][blk][n][row]; depth-2 prefetch ring, converted to float off-path
  const unsigned short* x0 = xw + (size_t)blk*2048;
  int xofs[4];
#pragma unroll
  for(int g=0;g<4;++g) xofs[g]=((g*128+cb)<<2)+lg;
  float pxf[4], p1f[4];
#pragma unroll
  for(int g=0;g<4;++g) pxf[g]=ubits2f(((unsigned)x0[xofs[g]])<<16);
#pragma unroll
  for(int g=0;g<4;++g) p1f[g]=ubits2f(((unsigned)x0[32768+xofs[g]])<<16);
  // raw-h global store pointer (row bb+lg, col cb), advances 128/step
  unsigned short* hrp=hraw+((size_t)(bb+lg)<<17)+cb;
  float cc=0.f, hh=0.f;
  int cur=0;
  for(int t=0;t<1024;++t){
    const unsigned short* hc=hbuf[cur];
    // A-frags: A row i := h row (i>>2)  => C rows lg*4+r all equal gate(h-row lg) -> acc[.][0]
    s16x8 af[4];
#pragma unroll
    for(int kc=0;kc<4;++kc) af[kc]=*(const s16x8*)(hc+(lr>>2)*LPAD+kc*32+lg*8);
    // prefetch xW for t+2 (stays in flight across relaxed barriers)
    int t2=t+2<1024?t+2:1023;
    const unsigned short* xq=x0+(size_t)t2*32768;
    float pnf[4];
#pragma unroll
    for(int g=0;g<4;++g) pnf[g]=ubits2f(((unsigned)xq[xofs[g]])<<16);
    // single 4-deep chain per gate, C initialized with xW (kills post-add + zero-init)
    f32x4 acc[4];
#pragma unroll
    for(int g=0;g<4;++g){ f32x4 c={pxf[g],pxf[g],pxf[g],pxf[g]}; acc[g]=c; }
#pragma unroll
    for(int kc=0;kc<4;++kc)
#pragma unroll
      for(int g=0;g<4;++g)
        acc[g]=__builtin_amdgcn_mfma_f32_16x16x32_bf16(af[kc],wf[g][kc],acc[g],0,0,0);
    // gates: args pre-scaled so e2 is direct
    float ex[4];
#pragma unroll
    for(int g=0;g<4;++g){
      float a=acc[g][0];
      if (g==2) a=__builtin_amdgcn_fmed3f(a,-80.f,80.f);
      ex[g]=e2_(a);
      pxf[g]=p1f[g]; p1f[g]=pnf[g];
    }
    float sitg=rcp_((1.f+ex[0])*(1.f+ex[2]))*(1.f-ex[2]);  // sigmoid(i)*tanh(g)
    float sf=rcp_(1.f+ex[1]);
    cc=fmaf(sf,cc,sitg);
    float cl=__builtin_amdgcn_fmed3f(cc,-30.f,30.f);
    float E=e2_(cl*2.885390082f);
    hh=(E-1.f)*rcp_((1.f+ex[3])*(E+1.f));                  // sigmoid(o)*tanh(c)
    unsigned p;
    asm("v_cvt_pk_bf16_f32 %0, %1, %2":"=v"(p):"v"(hh),"v"(hh));
    unsigned short hb=(unsigned short)(p&0xffffu);
    hbuf[cur^1][lg*LPAD+cb]=hb;
    hrp[(size_t)t<<7]=hb;
    // barrier WITHOUT vmcnt drain: only LDS must settle; global ops stay in flight
    asm volatile("s_waitcnt lgkmcnt(0)\n\ts_barrier" ::: "memory");
    cur^=1;
  }
  hL[(size_t)(bb+lg)*128+cb]=hh;
}

// ---- LN(hraw) -> hln bf16; scores[b][s] = mask * sum_n w_aw[n]*tanh((hln @ G_b)[s][n]) ----
__global__ __launch_bounds__(512) void k_scores(const unsigned short* __restrict__ hraw,
    const unsigned short* __restrict__ gt, const float* __restrict__ hng, const float* __restrict__ hnb,
    const float* __restrict__ waw, const float* __restrict__ mask,
    unsigned short* __restrict__ hln, float* __restrict__ scores){
  __shared__ unsigned short As[128*PAD];
  __shared__ unsigned short Bs[128*PAD];
  __shared__ float redS[128][4];
  __shared__ float redQ[128][4];
  __shared__ float red[128][4];
  const int b=blockIdx.x>>3, s0=(blockIdx.x&7)*128;
  const int tid=threadIdx.x;
  const int i=tid>>2, kq=(tid&3)*32;
  u16x8 hv[4];
  { // load 32 bf16 of row (s0+i), partial stats
    const u16x8* src=(const u16x8*)(hraw+((size_t)b*1024+s0+i)*128+kq);
    float s=0.f,q=0.f;
#pragma unroll
    for(int j=0;j<4;++j){ hv[j]=src[j];
#pragma unroll
      for(int e=0;e<8;++e){ float x=bf2f(hv[j][e]); s+=x; q+=x*x; } }
    redS[i][tid&3]=s; redQ[i][tid&3]=q;
  }
  { // Bs load (G_b^T rows = n)
    const u16x4* src=(const u16x4*)(gt+(size_t)b*16384+i*128+kq);
#pragma unroll
    for(int j=0;j<8;++j) *(u16x4*)(Bs+i*PAD+kq+4*j)=src[j];
  }
  __syncthreads();
  { // finalize LN, write As + hln
    float s=redS[i][0]+redS[i][1]+redS[i][2]+redS[i][3];
    float q=redQ[i][0]+redQ[i][1]+redQ[i][2]+redQ[i][3];
    float m=s*(1.f/128.f);
    float inv=__builtin_amdgcn_rsqf(q*(1.f/128.f)-m*m+1e-5f);
    unsigned short* dst=hln+((size_t)b*1024+s0+i)*128+kq;
#pragma unroll
    for(int j=0;j<4;++j){ u16x8 o;
#pragma unroll
      for(int e=0;e<8;++e){ int d=kq+j*8+e;
        float x=(bf2f(hv[j][e])-m)*inv*hng[d]+hnb[d];
        o[e]=f2bf(x); }
      *(u16x8*)(As+i*PAD+kq+8*j)=o;
      *(u16x8*)(dst+8*j)=o;
    }
  }
  __syncthreads();
  f32x4 z={0.f,0.f,0.f,0.f};
  f32x4 acc[4][2]={{z,z},{z,z},{z,z},{z,z}};
  mfma128(As,Bs,acc);
  const int w=tid>>6,l=tid&63,wm=w>>2,wn=w&3,lr=l&15,lg=l>>4;
  const float w0=waw[wn*32+lr], w1=waw[wn*32+16+lr];
#pragma unroll
  for(int mt=0;mt<4;++mt){
    f32x4 p4;
#pragma unroll
    for(int r=0;r<4;++r) p4[r]=tanh_(acc[mt][0][r])*w0+tanh_(acc[mt][1][r])*w1;
#pragma unroll
    for(int m=1;m<16;m<<=1){
#pragma unroll
      for(int r=0;r<4;++r) p4[r]+=__shfl_xor(p4[r],m,64);
    }
    if (lr==0){
#pragma unroll
      for(int r=0;r<4;++r) red[wm*64+mt*16+lg*4+r][wn]=p4[r];
    }
  }
  __syncthreads();
  if (tid<128){
    float sc=red[tid][0]+red[tid][1]+red[tid][2]+red[tid][3];
    sc*=mask[b*1024+s0+tid];
    scores[b*1024+s0+tid]=sc;
  }
}

// ---- softmax over S + r_pre[b][d] = sum_s w_s hln[b][s][d] ----
__global__ __launch_bounds__(256) void k_wsum(const float* __restrict__ scores,
    const unsigned short* __restrict__ hln, float* __restrict__ rpre){
  __shared__ float wl[1024];
  __shared__ float red[256];
  __shared__ float part[8][32];
  const int b=blockIdx.x>>2, d0=(blockIdx.x&3)*32;
  const int tid=threadIdx.x;
  float v[4]; float lm=-1e30f;
#pragma unroll
  for(int q=0;q<4;++q){ v[q]=scores[b*1024+tid+256*q]; lm=fmaxf(lm,v[q]); }
  red[tid]=lm; __syncthreads();
  for(int st=128;st;st>>=1){ if(tid<st) red[tid]=fmaxf(red[tid],red[tid+st]); __syncthreads(); }
  const float mx=red[0]; __syncthreads();
  float ls=0.f;
#pragma unroll
  for(int q=0;q<4;++q){ v[q]=e2_((v[q]-mx)*1.442695041f); ls+=v[q]; }
  red[tid]=ls; __syncthreads();
  for(int st=128;st;st>>=1){ if(tid<st) red[tid]+=red[tid+st]; __syncthreads(); }
  const float inv=rcp_(red[0]);
#pragma unroll
  for(int q=0;q<4;++q) wl[tid+256*q]=v[q]*inv;
  __syncthreads();
  const int d=tid&31, sg=tid>>5;
  float acc=0.f;
  const unsigned short* hp=hln+(size_t)b*131072+d0+d;
  for(int s=sg*128;s<sg*128+128;++s) acc+=wl[s]*bf2f(hp[(size_t)s*128]);
  part[sg][d]=acc; __syncthreads();
  if (tid<32){
    float a=0.f;
#pragma unroll
    for(int g=0;g<8;++g) a+=part[g][tid];
    rpre[b*128+d0+tid]=a;
  }
}

// ---- r = tanh(rpre@W_rout^T + hL@W_hout^T); result = softmax(r@W_cls^T + b_cls) ----
__global__ __launch_bounds__(128) void k_final(const float* __restrict__ rpre, const float* __restrict__ hLp,
    const float* __restrict__ wrout, const float* __restrict__ whout, const float* __restrict__ wcls,
    const float* __restrict__ bcls, float* __restrict__ out){
  __shared__ float rv[128], hv[128], cred[4];
  const int b=blockIdx.x, n=threadIdx.x;
  rv[n]=rpre[b*128+n]; hv[n]=hLp[b*128+n];
  __syncthreads();
  float a=0.f;
  const float* wr=wrout+(size_t)n*128;
  const float* wh=whout+(size_t)n*128;
  for(int k=0;k<128;++k) a+=rv[k]*wr[k]+hv[k]*wh[k];
  const float rr=tanh_(a);
  out[128+b*128+n]=rr;
  float p0=rr*wcls[n], p1=rr*wcls[128+n];
#pragma unroll
  for(int m=1;m<64;m<<=1){ p0+=__shfl_xor(p0,m,64); p1+=__shfl_xor(p1,m,64); }
  if ((n&63)==0){ cred[(n>>6)*2]=p0; cred[(n>>6)*2+1]=p1; }
  __syncthreads();
  if (n==0){
    float l0=cred[0]+cred[2]+bcls[0], l1=cred[1]+cred[3]+bcls[1];
    float m=fmaxf(l0,l1);
    float e0=e2_((l0-m)*1.442695041f), e1=e2_((l1-m)*1.442695041f);
    float s=rcp_(e0+e1);
    out[b*2]=e0*s; out[b*2+1]=e1*s;
  }
}

extern "C" void kernel_launch(void* const* d_in, const int* in_sizes, int n_in,
                              void* d_out, int out_size, void* d_ws, size_t ws_size,
                              hipStream_t stream) {
  (void)in_sizes; (void)n_in; (void)out_size; (void)ws_size;
  const int*   new_list=(const int*)d_in[0];
  const float* new_mask=(const float*)d_in[1];
  const int*   aspect  =(const int*)d_in[2];
  // d_in[3] = gpunum (unused)
  const float* emb   =(const float*)d_in[4];
  const float* W_ih  =(const float*)d_in[5];
  const float* W_hh  =(const float*)d_in[6];
  const float* b_ih  =(const float*)d_in[7];
  const float* b_hh  =(const float*)d_in[8];
  const float* an_g  =(const float*)d_in[9];
  const float* an_b  =(const float*)d_in[10];
  const float* hn_g  =(const float*)d_in[11];
  const float* hn_b  =(const float*)d_in[12];
  const float* W_att =(const float*)d_in[13];
  const float* W_aw  =(const float*)d_in[14];
  const float* W_rout=(const float*)d_in[15];
  const float* W_hout=(const float*)d_in[16];
  const float* W_cls =(const float*)d_in[17];
  const float* b_cls =(const float*)d_in[18];
  float* out=(float*)d_out;
  char* ws=(char*)d_ws;
  // workspace layout (bytes)
  unsigned short* xw    =(unsigned short*)(ws);              // 1024*16*512*4*2 = 67108864
  unsigned short* hraw  =(unsigned short*)(ws+67108864);     // 64*1024*128*2  = 16777216
  unsigned short* hln   =(unsigned short*)(ws+83886080);     // 64*1024*128*2  = 16777216
  unsigned short* gt    =(unsigned short*)(ws+100663296);    // 64*128*128*2   = 2097152
  unsigned short* whh   =(unsigned short*)(ws+102760448);    // 512*128*2      = 131072
  float*          scores=(float*)(ws+102891520);             // 64*1024*4      = 262144
  float*          hLb   =(float*)(ws+103153664);             // 64*128*4       = 32768
  float*          rpre  =(float*)(ws+103186432);             // 64*128*4       = 32768
  k_cvt   <<<dim3(256),    dim3(256), 0, stream>>>(W_hh, whh, 512*128);
  k_aspg  <<<dim3(64),     dim3(512), 0, stream>>>(aspect, emb, an_g, an_b, W_att, gt);
  k_xw    <<<dim3(512,4),  dim3(512), 0, stream>>>(new_list, emb, W_ih, b_ih, b_hh, xw);
  k_lstm  <<<dim3(16),     dim3(512), 0, stream>>>(xw, whh, hraw, hLb);
  k_scores<<<dim3(512),    dim3(512), 0, stream>>>(hraw, gt, hn_g, hn_b, W_aw, new_mask, hln, scores);
  k_wsum  <<<dim3(256),    dim3(256), 0, stream>>>(scores, hln, rpre);
  k_final <<<dim3(64),     dim3(128), 0, stream>>>(rpre, hLb, W_rout, W_hout, W_cls, b_cls, out);
}

// Round 10
// 578.344 us; speedup vs baseline: 1.1746x; 1.1746x over previous
//
#include <hip/hip_runtime.h>

typedef __attribute__((ext_vector_type(8))) short s16x8;
typedef __attribute__((ext_vector_type(4))) float f32x4;
typedef __attribute__((ext_vector_type(4))) unsigned short u16x4;
typedef __attribute__((ext_vector_type(8))) unsigned short u16x8;

#define PAD 136   // GEMM-tile LDS row stride (2-way on 16-row reads = free)
#define LPAD 144  // k_lstm h-buffer stride: 288B -> row bank offset 8 -> dup-4 read conflict-free

__device__ __forceinline__ unsigned short f2bf(float f){
  union{float f;unsigned u;} v; v.f=f;
  unsigned r=v.u + 0x7fffu + ((v.u>>16)&1u);
  return (unsigned short)(r>>16);
}
__device__ __forceinline__ float bf2f(unsigned short u){
  union{unsigned u;float f;} v; v.u=((unsigned)u)<<16; return v.f;
}
__device__ __forceinline__ float ubits2f(unsigned u){
  union{unsigned u;float f;} v; v.u=u; return v.f;
}
__device__ __forceinline__ float rcp_(float x){ return __builtin_amdgcn_rcpf(x); }
__device__ __forceinline__ float e2_(float x){ return __builtin_amdgcn_exp2f(x); }
__device__ __forceinline__ float tanh_(float x){ return 1.f-2.f*rcp_(1.f+e2_(x*2.885390082f)); }

// 128x128x128 bf16 GEMM from LDS tiles. As: [128][PAD] rows=M, Bs: [128][PAD] rows=N (i.e. B^T).
// 8 waves = 2(M) x 4(N). acc[mt][nt]: C[row = wm*64+mt*16+(l>>4)*4+r][col = wn*32+nt*16+(l&15)]
__device__ __forceinline__ void mfma128(const unsigned short* As, const unsigned short* Bs, f32x4 acc[4][2]){
  const int tid=threadIdx.x, w=tid>>6, l=tid&63;
  const int wm=w>>2, wn=w&3, lr=l&15, lk=(l>>4)*8;
#pragma unroll
  for(int kc=0;kc<4;++kc){
    const int ko=kc*32+lk;
    s16x8 a[4], bb[2];
#pragma unroll
    for(int mt=0;mt<4;++mt) a[mt]=*(const s16x8*)(As+(wm*64+mt*16+lr)*PAD+ko);
#pragma unroll
    for(int nt=0;nt<2;++nt) bb[nt]=*(const s16x8*)(Bs+(wn*32+nt*16+lr)*PAD+ko);
#pragma unroll
    for(int mt=0;mt<4;++mt)
#pragma unroll
      for(int nt=0;nt<2;++nt)
        acc[mt][nt]=__builtin_amdgcn_mfma_f32_16x16x32_bf16(a[mt],bb[nt],acc[mt][nt],0,0,0);
  }
}

// ---- W_hh f32 -> bf16 ----
__global__ __launch_bounds__(256) void k_cvt(const float* __restrict__ w, unsigned short* __restrict__ o, int n){
  int i = blockIdx.x*256 + threadIdx.x;
  if (i<n) o[i] = f2bf(w[i]);
}

// ---- aspect LN + G_b = circulant(a_b) @ W_att^T, stored GT[b][n][k] bf16 ----
__global__ __launch_bounds__(512) void k_aspg(const int* __restrict__ aspect, const float* __restrict__ emb,
    const float* __restrict__ ang, const float* __restrict__ anb, const float* __restrict__ watt,
    unsigned short* __restrict__ gt){
  __shared__ unsigned short As[128*PAD];
  __shared__ unsigned short Bs[128*PAD];
  __shared__ float a_ln[128];
  __shared__ float stat[2];
  const int b=blockIdx.x, tid=threadIdx.x;
  if (tid<128) a_ln[tid] = emb[(size_t)aspect[b]*128 + tid];
  __syncthreads();
  if (tid==0){
    float s=0.f,q=0.f;
    for(int d=0;d<128;++d){ float v=a_ln[d]; s+=v; q+=v*v; }
    float m=s*(1.f/128.f);
    stat[0]=m; stat[1]=__builtin_amdgcn_rsqf(q*(1.f/128.f)-m*m+1e-5f);
  }
  __syncthreads();
  if (tid<128) a_ln[tid] = (a_ln[tid]-stat[0])*stat[1]*ang[tid]+anb[tid];
  __syncthreads();
  { // A = circulant: As[k][d] = a_ln[(d-k) & 127]
    int k=tid>>2, dq=(tid&3)*32;
    for(int d=dq; d<dq+32; ++d) As[k*PAD+d]=f2bf(a_ln[(d-k)&127]);
  }
  { // B^T rows = n: Bs[n][d] = W_att[n][d]
    int i=tid>>2, kq=(tid&3)*32;
    const f32x4* src=(const f32x4*)(watt+(size_t)i*128+kq);
#pragma unroll
    for(int j=0;j<8;++j){ f32x4 v=src[j]; u16x4 o;
#pragma unroll
      for(int q=0;q<4;++q) o[q]=f2bf(v[q]);
      *(u16x4*)(Bs+i*PAD+kq+4*j)=o; }
  }
  __syncthreads();
  f32x4 z={0.f,0.f,0.f,0.f};
  f32x4 acc[4][2]={{z,z},{z,z},{z,z},{z,z}};
  mfma128(As,Bs,acc);
  const int w=tid>>6,l=tid&63,wm=w>>2,wn=w&3,lr=l&15,lg=l>>4;
#pragma unroll
  for(int mt=0;mt<4;++mt)
#pragma unroll
    for(int nt=0;nt<2;++nt){
      int k0=wm*64+mt*16+lg*4;
      int n=wn*32+nt*16+lr;
      u16x4 o;
#pragma unroll
      for(int r=0;r<4;++r) o[r]=f2bf(acc[mt][nt][r]);
      *(u16x4*)(gt+(size_t)b*16384+n*128+k0)=o;
    }
}

// ---- xW = emb[tok] @ W_ih^T + b_ih + b_hh, stored bf16 as xw[t][blk16][n][row4] ----
__global__ __launch_bounds__(512) void k_xw(const int* __restrict__ new_list, const float* __restrict__ emb,
    const float* __restrict__ wih, const float* __restrict__ bih, const float* __restrict__ bhh,
    unsigned short* __restrict__ xw){
  __shared__ unsigned short As[128*PAD];
  __shared__ unsigned short Bs[128*PAD];
  const int tid=threadIdx.x;
  const int m0=blockIdx.x*128, n0=blockIdx.y*128;
  { // A: gathered emb rows (token for (t,b), m = t*64+b)
    int i=tid>>2, kq=(tid&3)*32;
    int m=m0+i, t=m>>6, b=m&63;
    int tok=new_list[b*1024+t];
    const f32x4* src=(const f32x4*)(emb+(size_t)tok*128+kq);
#pragma unroll
    for(int j=0;j<8;++j){ f32x4 v=src[j]; u16x4 o;
#pragma unroll
      for(int q=0;q<4;++q) o[q]=f2bf(v[q]);
      *(u16x4*)(As+i*PAD+kq+4*j)=o; }
  }
  { // B^T rows = n: W_ih[n][k]
    int i=tid>>2, kq=(tid&3)*32;
    const f32x4* src=(const f32x4*)(wih+(size_t)(n0+i)*128+kq);
#pragma unroll
    for(int j=0;j<8;++j){ f32x4 v=src[j]; u16x4 o;
#pragma unroll
      for(int q=0;q<4;++q) o[q]=f2bf(v[q]);
      *(u16x4*)(Bs+i*PAD+kq+4*j)=o; }
  }
  __syncthreads();
  f32x4 z={0.f,0.f,0.f,0.f};
  f32x4 acc[4][2]={{z,z},{z,z},{z,z},{z,z}};
  mfma128(As,Bs,acc);
  const int w=tid>>6,l=tid&63,wm=w>>2,wn=w&3,lr=l&15,lg=l>>4;
#pragma unroll
  for(int nt=0;nt<2;++nt){
    int n=n0+wn*32+nt*16+lr;
    float bias=bih[n]+bhh[n];
#pragma unroll
    for(int mt=0;mt<4;++mt){
      int m_=m0+wm*64+mt*16+lg*4;
      int t=m_>>6, b0=m_&63;           // b0 is 4-aligned, rows b0..b0+3 same t
      u16x4 o;
#pragma unroll
      for(int r=0;r<4;++r) o[r]=f2bf(acc[mt][nt][r]+bias);
      // layout: [t][b0>>2][n][b0&3]
      *(u16x4*)(xw+(((size_t)t*16+(b0>>2))*512+n)*4)=o;
    }
  }
}

// ---- recurrent LSTM: 16 blocks x 4 batch, dup-x4 A rows (lr>>2 map); relaxed barrier. ----
__global__ __launch_bounds__(512) void k_lstm(const unsigned short* __restrict__ xw,
    const unsigned short* __restrict__ whh,
    unsigned short* __restrict__ hraw, float* __restrict__ hL){
  __shared__ unsigned short hbuf[2][4*LPAD];
  const int tid=threadIdx.x, w=tid>>6, l=tid&63, lr=l&15, lg=l>>4;
  const int blk=blockIdx.x, bb=blk*4;
  const int cb=w*16+lr;                       // h column this lane owns
  // W_hh B-fragments in registers (step-invariant). wave w owns h-cols w*16..+15 of each gate.
  s16x8 wf[4][4];
#pragma unroll
  for(int g=0;g<4;++g)
#pragma unroll
    for(int kc=0;kc<4;++kc)
      wf[g][kc]=*(const s16x8*)(whh+(size_t)(g*128+cb)*128+kc*32+lg*8);
  for(int i=tid;i<2*4*LPAD;i+=512) ((unsigned short*)hbuf)[i]=0;
  __syncthreads();
  // xw addressing: [t][blk][n][row]; depth-2 prefetch ring
  const unsigned short* x0 = xw + (size_t)blk*2048;
  int xofs[4];
#pragma unroll
  for(int g=0;g<4;++g) xofs[g]=((g*128+cb)<<2)+lg;
  unsigned short px[4], p1[4];
#pragma unroll
  for(int g=0;g<4;++g) px[g]=x0[xofs[g]];
#pragma unroll
  for(int g=0;g<4;++g) p1[g]=x0[32768+xofs[g]];
  // raw-h global store pointer (row bb+lg, col cb), advances 128/step
  unsigned short* hrp=hraw+((size_t)(bb+lg)<<17)+cb;
  float cc=0.f, hh=0.f;
  int cur=0;
  const float L2E=1.442695041f;
  for(int t=0;t<1024;++t){
    const unsigned short* hc=hbuf[cur];
    // A-frags: A row i := h row (i>>2)  => C rows lg*4+r all equal gate(h-row lg) -> acc[g][0]
    s16x8 af[4];
#pragma unroll
    for(int kc=0;kc<4;++kc) af[kc]=*(const s16x8*)(hc+(lr>>2)*LPAD+kc*32+lg*8);
    // prefetch xW for t+2 (stays in flight across relaxed barriers)
    { int t2=t+2<1024?t+2:1023;
      const unsigned short* xq=x0+(size_t)t2*32768;
      unsigned short pn[4];
#pragma unroll
      for(int g=0;g<4;++g) pn[g]=xq[xofs[g]];
      f32x4 z={0.f,0.f,0.f,0.f};
      f32x4 acc[4]={z,z,z,z};
#pragma unroll
      for(int kc=0;kc<4;++kc)
#pragma unroll
        for(int g=0;g<4;++g)
          acc[g]=__builtin_amdgcn_mfma_f32_16x16x32_bf16(af[kc],wf[g][kc],acc[g],0,0,0);
      float ga[4];
#pragma unroll
      for(int g=0;g<4;++g){
        ga[g]=acc[g][0]+ubits2f(((unsigned)px[g])<<16);
        px[g]=p1[g]; p1[g]=pn[g];
      }
      float gg=__builtin_amdgcn_fmed3f(ga[2],-30.f,30.f);
      float ei=e2_(ga[0]*-L2E), eg=e2_(gg*(-2.f*L2E));
      float sitg=rcp_((1.f+ei)*(1.f+eg))*(1.f-eg);   // sigmoid(i)*tanh(g)
      float sf=rcp_(1.f+e2_(ga[1]*-L2E));
      cc=fmaf(sf,cc,sitg);
      float cl=__builtin_amdgcn_fmed3f(cc,-30.f,30.f);
      float E=e2_(cl*(2.f*L2E)), eo=e2_(ga[3]*-L2E);
      hh=(E-1.f)*rcp_((1.f+eo)*(E+1.f));             // sigmoid(o)*tanh(c)
    }
    unsigned p;
    asm("v_cvt_pk_bf16_f32 %0, %1, %2":"=v"(p):"v"(hh),"v"(hh));
    unsigned short hb=(unsigned short)(p&0xffffu);
    hbuf[cur^1][lg*LPAD+cb]=hb;
    hrp[(size_t)t<<7]=hb;
    // barrier WITHOUT vmcnt drain: only LDS (lgkm) must settle; global ops stay in flight
    asm volatile("s_waitcnt lgkmcnt(0)\n\ts_barrier" ::: "memory");
    cur^=1;
  }
  hL[(size_t)(bb+lg)*128+cb]=hh;
}

// ---- LN(hraw) -> hln bf16; scores[b][s] = mask * sum_n w_aw[n]*tanh((hln @ G_b)[s][n]) ----
__global__ __launch_bounds__(512) void k_scores(const unsigned short* __restrict__ hraw,
    const unsigned short* __restrict__ gt, const float* __restrict__ hng, const float* __restrict__ hnb,
    const float* __restrict__ waw, const float* __restrict__ mask,
    unsigned short* __restrict__ hln, float* __restrict__ scores){
  __shared__ unsigned short As[128*PAD];
  __shared__ unsigned short Bs[128*PAD];
  __shared__ float redS[128][4];
  __shared__ float redQ[128][4];
  __shared__ float red[128][4];
  const int b=blockIdx.x>>3, s0=(blockIdx.x&7)*128;
  const int tid=threadIdx.x;
  const int i=tid>>2, kq=(tid&3)*32;
  u16x8 hv[4];
  { // load 32 bf16 of row (s0+i), partial stats
    const u16x8* src=(const u16x8*)(hraw+((size_t)b*1024+s0+i)*128+kq);
    float s=0.f,q=0.f;
#pragma unroll
    for(int j=0;j<4;++j){ hv[j]=src[j];
#pragma unroll
      for(int e=0;e<8;++e){ float x=bf2f(hv[j][e]); s+=x; q+=x*x; } }
    redS[i][tid&3]=s; redQ[i][tid&3]=q;
  }
  { // Bs load (G_b^T rows = n)
    const u16x4* src=(const u16x4*)(gt+(size_t)b*16384+i*128+kq);
#pragma unroll
    for(int j=0;j<8;++j) *(u16x4*)(Bs+i*PAD+kq+4*j)=src[j];
  }
  __syncthreads();
  { // finalize LN, write As + hln
    float s=redS[i][0]+redS[i][1]+redS[i][2]+redS[i][3];
    float q=redQ[i][0]+redQ[i][1]+redQ[i][2]+redQ[i][3];
    float m=s*(1.f/128.f);
    float inv=__builtin_amdgcn_rsqf(q*(1.f/128.f)-m*m+1e-5f);
    unsigned short* dst=hln+((size_t)b*1024+s0+i)*128+kq;
#pragma unroll
    for(int j=0;j<4;++j){ u16x8 o;
#pragma unroll
      for(int e=0;e<8;++e){ int d=kq+j*8+e;
        float x=(bf2f(hv[j][e])-m)*inv*hng[d]+hnb[d];
        o[e]=f2bf(x); }
      *(u16x8*)(As+i*PAD+kq+8*j)=o;
      *(u16x8*)(dst+8*j)=o;
    }
  }
  __syncthreads();
  f32x4 z={0.f,0.f,0.f,0.f};
  f32x4 acc[4][2]={{z,z},{z,z},{z,z},{z,z}};
  mfma128(As,Bs,acc);
  const int w=tid>>6,l=tid&63,wm=w>>2,wn=w&3,lr=l&15,lg=l>>4;
  const float w0=waw[wn*32+lr], w1=waw[wn*32+16+lr];
#pragma unroll
  for(int mt=0;mt<4;++mt){
    f32x4 p4;
#pragma unroll
    for(int r=0;r<4;++r) p4[r]=tanh_(acc[mt][0][r])*w0+tanh_(acc[mt][1][r])*w1;
#pragma unroll
    for(int m=1;m<16;m<<=1){
#pragma unroll
      for(int r=0;r<4;++r) p4[r]+=__shfl_xor(p4[r],m,64);
    }
    if (lr==0){
#pragma unroll
      for(int r=0;r<4;++r) red[wm*64+mt*16+lg*4+r][wn]=p4[r];
    }
  }
  __syncthreads();
  if (tid<128){
    float sc=red[tid][0]+red[tid][1]+red[tid][2]+red[tid][3];
    sc*=mask[b*1024+s0+tid];
    scores[b*1024+s0+tid]=sc;
  }
}

// ---- softmax over S + r_pre[b][d] = sum_s w_s hln[b][s][d] ----
__global__ __launch_bounds__(256) void k_wsum(const float* __restrict__ scores,
    const unsigned short* __restrict__ hln, float* __restrict__ rpre){
  __shared__ float wl[1024];
  __shared__ float red[256];
  __shared__ float part[8][32];
  const int b=blockIdx.x>>2, d0=(blockIdx.x&3)*32;
  const int tid=threadIdx.x;
  float v[4]; float lm=-1e30f;
#pragma unroll
  for(int q=0;q<4;++q){ v[q]=scores[b*1024+tid+256*q]; lm=fmaxf(lm,v[q]); }
  red[tid]=lm; __syncthreads();
  for(int st=128;st;st>>=1){ if(tid<st) red[tid]=fmaxf(red[tid],red[tid+st]); __syncthreads(); }
  const float mx=red[0]; __syncthreads();
  float ls=0.f;
#pragma unroll
  for(int q=0;q<4;++q){ v[q]=e2_((v[q]-mx)*1.442695041f); ls+=v[q]; }
  red[tid]=ls; __syncthreads();
  for(int st=128;st;st>>=1){ if(tid<st) red[tid]+=red[tid+st]; __syncthreads(); }
  const float inv=rcp_(red[0]);
#pragma unroll
  for(int q=0;q<4;++q) wl[tid+256*q]=v[q]*inv;
  __syncthreads();
  const int d=tid&31, sg=tid>>5;
  float acc=0.f;
  const unsigned short* hp=hln+(size_t)b*131072+d0+d;
  for(int s=sg*128;s<sg*128+128;++s) acc+=wl[s]*bf2f(hp[(size_t)s*128]);
  part[sg][d]=acc; __syncthreads();
  if (tid<32){
    float a=0.f;
#pragma unroll
    for(int g=0;g<8;++g) a+=part[g][tid];
    rpre[b*128+d0+tid]=a;
  }
}

// ---- r = tanh(rpre@W_rout^T + hL@W_hout^T); result = softmax(r@W_cls^T + b_cls) ----
__global__ __launch_bounds__(128) void k_final(const float* __restrict__ rpre, const float* __restrict__ hLp,
    const float* __restrict__ wrout, const float* __restrict__ whout, const float* __restrict__ wcls,
    const float* __restrict__ bcls, float* __restrict__ out){
  __shared__ float rv[128], hv[128], cred[4];
  const int b=blockIdx.x, n=threadIdx.x;
  rv[n]=rpre[b*128+n]; hv[n]=hLp[b*128+n];
  __syncthreads();
  float a=0.f;
  const float* wr=wrout+(size_t)n*128;
  const float* wh=whout+(size_t)n*128;
  for(int k=0;k<128;++k) a+=rv[k]*wr[k]+hv[k]*wh[k];
  const float rr=tanh_(a);
  out[128+b*128+n]=rr;
  float p0=rr*wcls[n], p1=rr*wcls[128+n];
#pragma unroll
  for(int m=1;m<64;m<<=1){ p0+=__shfl_xor(p0,m,64); p1+=__shfl_xor(p1,m,64); }
  if ((n&63)==0){ cred[(n>>6)*2]=p0; cred[(n>>6)*2+1]=p1; }
  __syncthreads();
  if (n==0){
    float l0=cred[0]+cred[2]+bcls[0], l1=cred[1]+cred[3]+bcls[1];
    float m=fmaxf(l0,l1);
    float e0=e2_((l0-m)*1.442695041f), e1=e2_((l1-m)*1.442695041f);
    float s=rcp_(e0+e1);
    out[b*2]=e0*s; out[b*2+1]=e1*s;
  }
}

extern "C" void kernel_launch(void* const* d_in, const int* in_sizes, int n_in,
                              void* d_out, int out_size, void* d_ws, size_t ws_size,
                              hipStream_t stream) {
  (void)in_sizes; (void)n_in; (void)out_size; (void)ws_size;
  const int*   new_list=(const int*)d_in[0];
  const float* new_mask=(const float*)d_in[1];
  const int*   aspect  =(const int*)d_in[2];
  // d_in[3] = gpunum (unused)
  const float* emb   =(const float*)d_in[4];
  const float* W_ih  =(const float*)d_in[5];
  const float* W_hh  =(const float*)d_in[6];
  const float* b_ih  =(const float*)d_in[7];
  const float* b_hh  =(const float*)d_in[8];
  const float* an_g  =(const float*)d_in[9];
  const float* an_b  =(const float*)d_in[10];
  const float* hn_g  =(const float*)d_in[11];
  const float* hn_b  =(const float*)d_in[12];
  const float* W_att =(const float*)d_in[13];
  const float* W_aw  =(const float*)d_in[14];
  const float* W_rout=(const float*)d_in[15];
  const float* W_hout=(const float*)d_in[16];
  const float* W_cls =(const float*)d_in[17];
  const float* b_cls =(const float*)d_in[18];
  float* out=(float*)d_out;
  char* ws=(char*)d_ws;
  // workspace layout (bytes)
  unsigned short* xw    =(unsigned short*)(ws);              // 1024*16*512*4*2 = 67108864
  unsigned short* hraw  =(unsigned short*)(ws+67108864);     // 64*1024*128*2  = 16777216
  unsigned short* hln   =(unsigned short*)(ws+83886080);     // 64*1024*128*2  = 16777216
  unsigned short* gt    =(unsigned short*)(ws+100663296);    // 64*128*128*2   = 2097152
  unsigned short* whh   =(unsigned short*)(ws+102760448);    // 512*128*2      = 131072
  float*          scores=(float*)(ws+102891520);             // 64*1024*4      = 262144
  float*          hLb   =(float*)(ws+103153664);             // 64*128*4       = 32768
  float*          rpre  =(float*)(ws+103186432);             // 64*128*4       = 32768
  k_cvt   <<<dim3(256),    dim3(256), 0, stream>>>(W_hh, whh, 512*128);
  k_aspg  <<<dim3(64),     dim3(512), 0, stream>>>(aspect, emb, an_g, an_b, W_att, gt);
  k_xw    <<<dim3(512,4),  dim3(512), 0, stream>>>(new_list, emb, W_ih, b_ih, b_hh, xw);
  k_lstm  <<<dim3(16),     dim3(512), 0, stream>>>(xw, whh, hraw, hLb);
  k_scores<<<dim3(512),    dim3(512), 0, stream>>>(hraw, gt, hn_g, hn_b, W_aw, new_mask, hln, scores);
  k_wsum  <<<dim3(256),    dim3(256), 0, stream>>>(scores, hln, rpre);
  k_final <<<dim3(64),     dim3(128), 0, stream>>>(rpre, hLb, W_rout, W_hout, W_cls, b_cls, out);
}